// Round 7
// baseline (438.250 us; speedup 1.0000x reference)
//
#include <hip/hip_runtime.h>

// LIF recurrence: X [B,T,N] f32 -> spikes [B,T,N] f32. B=32, T=64, N=32768.
// Independent per (b,n); sequential over t.
//
// R9 theory: X (248.6 MB) nearly fits the 268 MB L3, and the bench re-runs
// on the same X -- yet FETCH_SIZE=132MB says only half the reads hit L3.
// The 256 MB spike WRITE stream (never re-read) flows through L3 and evicts
// half of X every iteration. Fix: nontemporal stores to keep the write
// stream out of L3, leaving X resident -> reads become L3 hits.
//
// Why nt is safe NOW (vs R2's +33us regression): R2 was a ROLLING pipeline
// (load(t+4); compute; store(t)) -- vmcnt is one in-order queue, so every
// load-wait sat behind younger slow-retiring nt stores. Here (R5 burst
// structure) ALL 64 loads issue before ANY store: load waits count only
// loads; nt store retirement is invisible until the endpgm drain
// (amortized over the wave's whole lifetime). Single-variable A/B vs R5
// (~139us): only the store instruction changes.
//
// Pipeline history: R0 float2 d2 ~153us; R3 float4 d4 178us (occupancy
// halved, worse); R5 scalar full-burst ~139us; R6 ping-pong neutral.
// Wave slots / prefetch depth / wait ordering are exhausted levers; the
// write-side cache pollution is the remaining addressable cost.
// Strict fp preserved (contract off, true /5.0f divide): absmax must stay 0.

constexpr int B = 32;
constexpr int T = 64;
constexpr int N = 32768;
constexpr int NTHREADS = B * N;      // 1,048,576 threads = 16384 waves

__global__ __launch_bounds__(256) void lif_kernel(const float* __restrict__ X,
                                                  float* __restrict__ out) {
    // Match numpy's separately-rounded mul/add (no FMA contraction): fusing
    // changes rounding and can flip threshold decisions.
#pragma clang fp contract(off)
    const int i = blockIdx.x * blockDim.x + threadIdx.x;  // [0, B*N)
    const int b = i >> 15;               // i / N   (N = 32768)
    const int n = i & (N - 1);           // i % N
    const int base = b * (T * N) + n;    // <= 67.1M floats -> fits int

    const float* __restrict__ Xp = X + base;
    float* __restrict__ Op = out + base;

    // Phase 1: issue the ENTIRE read burst. Fully unrolled, constant
    // indices -> xs[] promotes to 64 VGPRs (runtime indexing would spill).
    float xs[T];
#pragma unroll
    for (int t = 0; t < T; ++t) {
        xs[t] = Xp[t * N];
    }

    // Fence: nothing from below may be scheduled before this point, so no
    // store (or compute) can be interleaved ahead of any load issue.
    __builtin_amdgcn_sched_barrier(0);

    // Phase 2: sequential LIF over t, storing each spike as computed.
    // nt store: bypass/evict-first in L2+L3 so the write stream does not
    // evict X from the Infinity Cache. All loads are older than all
    // stores, so load waits never include store retirement.
    float mem = 0.f, ca = 0.f;
#pragma unroll
    for (int t = 0; t < T; ++t) {
        float m = mem / 5.0f + (1.0f + 0.1f * ca) * xs[t];
        float s = ((m - 0.5f) > 0.0f) ? 1.0f : 0.0f;
        mem = (1.0f - s) * m;
        ca = 0.5f * ca + (1.0f - s);
        __builtin_nontemporal_store(s, Op + t * N);
    }
}

extern "C" void kernel_launch(void* const* d_in, const int* in_sizes, int n_in,
                              void* d_out, int out_size, void* d_ws, size_t ws_size,
                              hipStream_t stream) {
    const float* X = (const float*)d_in[0];
    float* out = (float*)d_out;
    const int block = 256;
    const int grid = NTHREADS / block;  // 4096 blocks
    lif_kernel<<<grid, block, 0, stream>>>(X, out);
}